// Round 3
// baseline (314.298 us; speedup 1.0000x reference)
//
#include <hip/hip_runtime.h>
#include <math.h>

typedef __bf16 bf16;
typedef __bf16 bf16x4 __attribute__((ext_vector_type(4)));
typedef __bf16 bf16x8 __attribute__((ext_vector_type(8)));
typedef float f32x4 __attribute__((ext_vector_type(4)));

#define MODE_QKV    0
#define MODE_SCORES 1
#define MODE_PV     2

__device__ inline void gload_lds16(const bf16* g, bf16* l) {
    __builtin_amdgcn_global_load_lds(
        (const __attribute__((address_space(1))) void*)g,
        (__attribute__((address_space(3))) void*)l, 16, 0, 0);
}

// Inline-asm LDS read: invisible to the compiler's waitcnt inserter, so the
// DMA-alias logic cannot inject vmcnt(0) drains before it. We supply the
// lgkmcnt waits manually (+ sched_barrier per rule 18).
__device__ inline bf16x8 ds_read16(const bf16* p) {
    bf16x8 r;
    asm volatile("ds_read_b128 %0, %1"
        : "=v"(r)
        : "v"((const __attribute__((address_space(3))) bf16*)p));
    return r;
}

// NT GEMM, 256x128 tile, BK=32, 4 waves (2M x 2N), per-wave 128x64 output,
// MFMA 16x16x32.  R2-proven 3-slot ring + counted vmcnt, now with 4
// quadrant-phases per K-tile (fine ds_read || global_load_lds || MFMA
// interleave, m201-style):
//   iter t: slot cs=t%3 computed, slot ss=(t+2)%3 staged (6 loads/thread,
//   spread 2/2/1/1 over the 4 phases).  Each phase:
//     {stage issue; asm ds_reads; s_barrier; lgkmcnt(0)+sched_barrier;
//      setprio(1); 8 MFMA (one C-quadrant); setprio(0)}
//   Tile end: s_waitcnt vmcnt(6) (tile t+1's 6 loads landed, t+2's still
//   flying -- never drains to 0 mid-loop), final s_barrier.
// Fragment reuse across quadrants: reads per phase = 6 / 2 / 4 / 0.
// LDS chunk-XOR swizzle (proven 0-conflict): slot q of row r holds global
// 16B chunk q ^ ((r>>1)&3); staging pre-swizzles the global source address.
// MODE_QKV:    C = bf16(acc + bias[col])
// MODE_SCORES: C = bf16(exp(alpha*acc))
// MODE_PV:     C = fp32 acc
template <int MODE>
__global__ __launch_bounds__(256, 2) void mfma_nt(
    const bf16* __restrict__ A, const bf16* __restrict__ B,
    const float* __restrict__ bias, void* __restrict__ Cv,
    int K, int lda, int ldb, int ldc,
    long sA, long sB, long sC, float alpha)
{
    constexpr int ASLOT = 256 * 32;   // elements per A ring slot (16 KiB)
    constexpr int BSLOT = 128 * 32;   // elements per B ring slot (8 KiB)

    A += (long)blockIdx.z * sA;
    B += (long)blockIdx.z * sB;

    __shared__ bf16 As[3 * ASLOT] __attribute__((aligned(16)));
    __shared__ bf16 Bs[3 * BSLOT] __attribute__((aligned(16)));

    const int t  = threadIdx.x;
    const int m0 = blockIdx.y * 256;
    const int n0 = blockIdx.x * 128;

    const int lane = t & 63;
    const int wave = t >> 6;
    const int wr   = (wave >> 1) * 128;  // wave row origin (M)
    const int wc   = (wave & 1) * 64;    // wave col origin (N)
    const int fr   = lane & 15;
    const int kq8  = lane >> 4;          // which 8-k chunk this lane's quad wants

    // staging decomposition: chunk c -> row c>>2, slot c&3,
    // global k8-chunk = slot ^ ((row>>1)&3)
    const bf16* gA[4];
    const bf16* gB[2];
#pragma unroll
    for (int l = 0; l < 4; l++) {
        const int c = t + 256 * l;
        const int r = c >> 2;
        const int k8 = ((c & 3) ^ ((r >> 1) & 3)) * 8;
        gA[l] = A + (long)(m0 + r) * lda + k8;
    }
#pragma unroll
    for (int l = 0; l < 2; l++) {
        const int c = t + 256 * l;
        const int r = c >> 2;
        const int k8 = ((c & 3) ^ ((r >> 1) & 3)) * 8;
        gB[l] = B + (long)(n0 + r) * ldb + k8;
    }

    // per-thread fragment element-offsets within a slot (swizzle folded in)
    int offA[8], offB[4];
#pragma unroll
    for (int i = 0; i < 8; i++) {
        const int r = wr + i * 16 + fr;
        offA[i] = (r * 4 + (kq8 ^ ((r >> 1) & 3))) * 8;
    }
#pragma unroll
    for (int j = 0; j < 4; j++) {
        const int r = wc + j * 16 + fr;
        offB[j] = (r * 4 + (kq8 ^ ((r >> 1) & 3))) * 8;
    }

    const int NT = K / 32;

#define STA(l, ss_, tt_) \
    gload_lds16(gA[l] + (long)(tt_) * 32, &As[(ss_) * ASLOT + (t + 256 * (l)) * 8])
#define STB(l, ss_, tt_) \
    gload_lds16(gB[l] + (long)(tt_) * 32, &Bs[(ss_) * BSLOT + (t + 256 * (l)) * 8])

    f32x4 acc[8][4] = {};

    // prologue: tiles 0,1 in flight (6 loads each); force 0 landed
    STA(0,0,0); STA(1,0,0); STA(2,0,0); STA(3,0,0); STB(0,0,0); STB(1,0,0);
    STA(0,1,1); STA(1,1,1); STA(2,1,1); STA(3,1,1); STB(0,1,1); STB(1,1,1);
    asm volatile("s_waitcnt vmcnt(6)" ::: "memory");
    __builtin_amdgcn_s_barrier();

    int cs = 0;                                   // current slot = tt % 3
    for (int tt = 0; tt < NT; ++tt) {
        const int ss = (cs >= 1) ? cs - 1 : 2;    // stage slot = (tt+2) % 3
        const bool st = (tt + 2 < NT);
        const bf16* as = &As[cs * ASLOT];
        const bf16* bs = &Bs[cs * BSLOT];

        bf16x8 af[8], bq[4];

        // ---- phase 0: stage A quarters 0,1; read A0-3,B0-1; MFMA q(0,0) --
        if (st) { STA(0, ss, tt + 2); STA(1, ss, tt + 2); }
        af[0] = ds_read16(as + offA[0]);
        af[1] = ds_read16(as + offA[1]);
        af[2] = ds_read16(as + offA[2]);
        af[3] = ds_read16(as + offA[3]);
        bq[0] = ds_read16(bs + offB[0]);
        bq[1] = ds_read16(bs + offB[1]);
        __builtin_amdgcn_s_barrier();
        asm volatile("s_waitcnt lgkmcnt(0)" ::: "memory");
        __builtin_amdgcn_sched_barrier(0);
        __builtin_amdgcn_s_setprio(1);
#pragma unroll
        for (int i = 0; i < 4; i++)
#pragma unroll
            for (int j = 0; j < 2; j++)
                acc[i][j] = __builtin_amdgcn_mfma_f32_16x16x32_bf16(
                    af[i], bq[j], acc[i][j], 0, 0, 0);
        __builtin_amdgcn_s_setprio(0);

        // ---- phase 1: stage A quarters 2,3; read B2-3; MFMA q(0,1) -------
        if (st) { STA(2, ss, tt + 2); STA(3, ss, tt + 2); }
        bq[2] = ds_read16(bs + offB[2]);
        bq[3] = ds_read16(bs + offB[3]);
        __builtin_amdgcn_s_barrier();
        asm volatile("s_waitcnt lgkmcnt(0)" ::: "memory");
        __builtin_amdgcn_sched_barrier(0);
        __builtin_amdgcn_s_setprio(1);
#pragma unroll
        for (int i = 0; i < 4; i++)
#pragma unroll
            for (int j = 2; j < 4; j++)
                acc[i][j] = __builtin_amdgcn_mfma_f32_16x16x32_bf16(
                    af[i], bq[j], acc[i][j], 0, 0, 0);
        __builtin_amdgcn_s_setprio(0);

        // ---- phase 2: stage B half 0; read A4-7; MFMA q(1,0) -------------
        if (st) { STB(0, ss, tt + 2); }
        af[4] = ds_read16(as + offA[4]);
        af[5] = ds_read16(as + offA[5]);
        af[6] = ds_read16(as + offA[6]);
        af[7] = ds_read16(as + offA[7]);
        __builtin_amdgcn_s_barrier();
        asm volatile("s_waitcnt lgkmcnt(0)" ::: "memory");
        __builtin_amdgcn_sched_barrier(0);
        __builtin_amdgcn_s_setprio(1);
#pragma unroll
        for (int i = 4; i < 8; i++)
#pragma unroll
            for (int j = 0; j < 2; j++)
                acc[i][j] = __builtin_amdgcn_mfma_f32_16x16x32_bf16(
                    af[i], bq[j], acc[i][j], 0, 0, 0);
        __builtin_amdgcn_s_setprio(0);

        // ---- phase 3: stage B half 1; MFMA q(1,1) (all frags in regs) ----
        if (st) { STB(1, ss, tt + 2); }
        __builtin_amdgcn_s_barrier();
        __builtin_amdgcn_s_setprio(1);
#pragma unroll
        for (int i = 4; i < 8; i++)
#pragma unroll
            for (int j = 2; j < 4; j++)
                acc[i][j] = __builtin_amdgcn_mfma_f32_16x16x32_bf16(
                    af[i], bq[j], acc[i][j], 0, 0, 0);
        __builtin_amdgcn_s_setprio(0);

        // tile-end counted wait: tile t+1 landed; tile t+2 stays in flight.
        if (st)
            asm volatile("s_waitcnt vmcnt(6)" ::: "memory");
        else
            asm volatile("s_waitcnt vmcnt(0)" ::: "memory");
        __builtin_amdgcn_s_barrier();

        cs = (cs < 2) ? cs + 1 : 0;
    }
#undef STA
#undef STB

    // C/D layout: col=lane&15, row=(lane>>4)*4+reg  [m89-verified]
    const int r4 = (lane >> 4) * 4;
    if constexpr (MODE == MODE_PV) {
        float* C = (float*)Cv + (long)blockIdx.z * sC;
#pragma unroll
        for (int j = 0; j < 4; j++) {
            const int col = n0 + wc + j * 16 + fr;
#pragma unroll
            for (int i = 0; i < 8; i++)
#pragma unroll
                for (int r = 0; r < 4; r++) {
                    const long row = m0 + wr + i * 16 + r4 + r;
                    C[row * ldc + col] = acc[i][j][r];
                }
        }
    } else {
        bf16* C = (bf16*)Cv + (long)blockIdx.z * sC;
#pragma unroll
        for (int j = 0; j < 4; j++) {
            const int col = n0 + wc + j * 16 + fr;
            const float bv = (MODE == MODE_QKV) ? bias[col] : 0.f;
#pragma unroll
            for (int i = 0; i < 8; i++)
#pragma unroll
                for (int r = 0; r < 4; r++) {
                    const long row = m0 + wr + i * 16 + r4 + r;
                    float v = acc[i][j][r];
                    if constexpr (MODE == MODE_QKV)
                        C[row * ldc + col] = (bf16)(v + bv);
                    else
                        C[row * ldc + col] = (bf16)__expf(alpha * v);
                }
        }
    }
}

__global__ __launch_bounds__(256) void f32_to_bf16(
    const float* __restrict__ in, bf16* __restrict__ out, long n)
{
    long i = ((long)blockIdx.x * 256 + threadIdx.x) * 4;
    if (i < n) {
        float4 v = *(const float4*)(in + i);
        bf16x4 o = { (bf16)v.x, (bf16)v.y, (bf16)v.z, (bf16)v.w };
        *(bf16x4*)(out + i) = o;
    }
}

// Vt[b][e][s] = V[b][s][e]; V has ld 3072 (inside qkv), Vt ld 2048.
__global__ __launch_bounds__(256) void transpose_v(
    const bf16* __restrict__ V, bf16* __restrict__ Vt)
{
    __shared__ bf16 tile[32][33];
    const bf16* Vb  = V  + (long)blockIdx.z * 2048 * 3072;
    bf16*       Vtb = Vt + (long)blockIdx.z * 1024 * 2048;
    const int s0 = blockIdx.x * 32, e0 = blockIdx.y * 32;
    const int tx = threadIdx.x & 31, ty = threadIdx.x >> 5;
#pragma unroll
    for (int i = 0; i < 32; i += 8)
        tile[ty + i][tx] = Vb[(long)(s0 + ty + i) * 3072 + e0 + tx];
    __syncthreads();
#pragma unroll
    for (int i = 0; i < 32; i += 8)
        Vtb[(long)(e0 + ty + i) * 2048 + s0 + tx] = tile[tx][ty + i];
}

// Per row: sum exp-scores, write fp32 out1 = Pu/l, renormalize Pu IN PLACE (bf16).
__global__ __launch_bounds__(256) void norm_rows(
    bf16* __restrict__ Pu, float* __restrict__ out1)
{
    bf16* p  = Pu   + (long)blockIdx.x * 2048;
    float* o = out1 + (long)blockIdx.x * 2048;
    const int t = threadIdx.x;
    bf16x8 v = *(const bf16x8*)(p + t * 8);
    float f[8];
    float s = 0.f;
#pragma unroll
    for (int k = 0; k < 8; k++) { f[k] = (float)v[k]; s += f[k]; }
#pragma unroll
    for (int off = 32; off > 0; off >>= 1) s += __shfl_xor(s, off);
    __shared__ float red[4];
    const int wid = t >> 6, lane = t & 63;
    if (lane == 0) red[wid] = s;
    __syncthreads();
    s = red[0] + red[1] + red[2] + red[3];
    const float inv = 1.0f / s;
    float4 a, b;
    a.x = f[0] * inv; a.y = f[1] * inv; a.z = f[2] * inv; a.w = f[3] * inv;
    b.x = f[4] * inv; b.y = f[5] * inv; b.z = f[6] * inv; b.w = f[7] * inv;
    *(float4*)(o + t * 8)     = a;
    *(float4*)(o + t * 8 + 4) = b;
    bf16x8 w;
#pragma unroll
    for (int k = 0; k < 8; k++) w[k] = (bf16)(f[k] * inv);
    *(bf16x8*)(p + t * 8) = w;
}

extern "C" void kernel_launch(void* const* d_in, const int* in_sizes, int n_in,
                              void* d_out, int out_size, void* d_ws, size_t ws_size,
                              hipStream_t stream)
{
    const int B = 4, S = 2048, E = 1024;
    const float* X    = (const float*)d_in[0];   // [B,S,E]
    const float* W    = (const float*)d_in[1];   // [3E,E]
    const float* bias = (const float*)d_in[2];   // [3E]

    float* out0 = (float*)d_out;                  // [B,S,E]
    float* out1 = out0 + (long)B * S * E;         // [B,S,S]

    // ws layout (bytes):
    //   [ 0M, 48M)  qkvb bf16 [B*S, 3072]
    //   [48M, 64M)  Vt   bf16 [B][E][S]
    //   [64M, 96M)  Pu   bf16 [B][S][S]  (exp-scores; renormalized in place)
    //   Xb [64M,80M) and Wb [80M,86.3M) overlap Pu — dead before Pu is written.
    char* ws = (char*)d_ws;
    bf16* qkvb = (bf16*)(ws);
    bf16* Vt   = (bf16*)(ws + 50331648);
    bf16* Pu   = (bf16*)(ws + 67108864);
    bf16* Xb   = (bf16*)(ws + 67108864);
    bf16* Wb   = (bf16*)(ws + 83886080);

    f32_to_bf16<<<(long)B * S * E / 1024, 256, 0, stream>>>(X, Xb, (long)B * S * E);
    f32_to_bf16<<<(long)3 * E * E / 1024, 256, 0, stream>>>(W, Wb, (long)3 * E * E);

    // qkvb = bf16(X @ W^T + b)   [M=8192, N=3072, K=1024] -> 32x24 = 768 blocks
    mfma_nt<MODE_QKV><<<dim3(3 * E / 128, B * S / 256, 1), 256, 0, stream>>>(
        Xb, Wb, bias, qkvb, E, E, E, 3 * E, 0, 0, 0, 1.0f);

    // Vt = V^T per batch
    transpose_v<<<dim3(S / 32, E / 32, B), 256, 0, stream>>>(qkvb + 2 * E, Vt);

    // Pu = bf16(exp(Q @ K^T / 32))  [2048x2048, K=1024] x4 -> 512 blocks
    mfma_nt<MODE_SCORES><<<dim3(S / 128, S / 256, B), 256, 0, stream>>>(
        qkvb, qkvb + E, nullptr, Pu, E, 3 * E, 3 * E, S,
        (long)S * 3 * E, (long)S * 3 * E, (long)S * S, 0.03125f);

    // out1 = Pu / rowsum  (fp32); Pu <- normalized bf16 in place
    norm_rows<<<B * S, 256, 0, stream>>>(Pu, out1);

    // out0 = P @ V  (= Pu @ Vt^T, NT)  [2048x1024, K=2048] x4 -> 256 blocks
    mfma_nt<MODE_PV><<<dim3(E / 128, S / 256, B), 256, 0, stream>>>(
        Pu, Vt, nullptr, out0, S, S, S, E,
        (long)S * S, (long)E * S, (long)S * E, 1.0f);
}

// Round 5
// 304.125 us; speedup vs baseline: 1.0335x; 1.0335x over previous
//
#include <hip/hip_runtime.h>
#include <math.h>

typedef __bf16 bf16;
typedef __bf16 bf16x4 __attribute__((ext_vector_type(4)));
typedef __bf16 bf16x8 __attribute__((ext_vector_type(8)));
typedef float f32x4 __attribute__((ext_vector_type(4)));

#define MODE_QKV    0
#define MODE_SCORES 1
#define MODE_PV     2

__device__ inline void gload_lds16(const bf16* g, bf16* l) {
    __builtin_amdgcn_global_load_lds(
        (const __attribute__((address_space(1))) void*)g,
        (__attribute__((address_space(3))) void*)l, 16, 0, 0);
}

// ds_read_b128 with a compile-time immediate offset. asm-opaque: the
// compiler's DMA-alias waitcnt inserter can't see it (rule 18); lgkm waits
// are supplied manually, each followed by sched_barrier(0).
#define DSR(dst, base, imm)                                                 \
    asm volatile("ds_read_b128 %0, %1 offset:%2"                            \
        : "=v"(dst)                                                         \
        : "v"((const __attribute__((address_space(3))) bf16*)(base)),       \
          "i"(imm))

#define MF(i, j) acc[i][j] = __builtin_amdgcn_mfma_f32_16x16x32_bf16(       \
    af[i], bq[j], acc[i][j], 0, 0, 0);

// NT GEMM, 256x128 tile, BK=32, 4 waves (2M x 2N), per-wave 128x64 output,
// MFMA 16x16x32, 3-slot LDS ring, 2-ahead prefetch, counted vmcnt(6).
// R4: K-loop unrolled x3 so ring slots are compile-time -> ALL 12 fragment
// reads per tile are ds_read_b128 base+offset:imm (zero per-tile VALU for
// LDS addressing; swizzle term (fr>>1)&3 is lane-constant so base is
// loop-invariant).  One read burst per tile; MFMA clusters gated by
// descending lgkmcnt(6)/(4)/(0); ONE s_barrier + ONE counted vmcnt per tile.
// LDS chunk-XOR swizzle (proven 0-conflict): slot q of row r holds global
// 16B chunk q ^ ((r>>1)&3); staging pre-swizzles the global source address.
// MODE_QKV:    C = bf16(acc + bias[col])
// MODE_SCORES: C = bf16(exp(alpha*acc))
// MODE_PV:     C = fp32 acc
template <int MODE, int NT>
__global__ __launch_bounds__(256, 2) void mfma_nt(
    const bf16* __restrict__ A, const bf16* __restrict__ B,
    const float* __restrict__ bias, void* __restrict__ Cv,
    int lda, int ldb, int ldc,
    long sA, long sB, long sC, float alpha)
{
    A += (long)blockIdx.z * sA;
    B += (long)blockIdx.z * sB;

    // 3 slots: A 256x32 (8192 el = 16 KiB), B 128x32 (4096 el = 8 KiB)
    __shared__ bf16 As[3 * 8192] __attribute__((aligned(16)));
    __shared__ bf16 Bs[3 * 4096] __attribute__((aligned(16)));

    const int t  = threadIdx.x;
    const int m0 = blockIdx.y * 256;
    const int n0 = blockIdx.x * 128;

    const int lane = t & 63;
    const int wave = t >> 6;
    const int wr   = (wave >> 1) * 128;  // wave row origin (M)
    const int wc   = (wave & 1) * 64;    // wave col origin (N)
    const int fr   = lane & 15;
    const int kq8  = lane >> 4;

    // staging decomposition: chunk c -> row c>>2, slot c&3,
    // global k8-chunk = slot ^ ((row>>1)&3)
    const bf16* gA0; const bf16* gA1; const bf16* gA2; const bf16* gA3;
    const bf16* gB0; const bf16* gB1;
    {
        const int c0 = t,        r0 = c0 >> 2, h0 = ((c0 & 3) ^ ((r0 >> 1) & 3)) * 8;
        const int c1 = t + 256,  r1 = c1 >> 2, h1 = ((c1 & 3) ^ ((r1 >> 1) & 3)) * 8;
        const int c2 = t + 512,  r2 = c2 >> 2, h2 = ((c2 & 3) ^ ((r2 >> 1) & 3)) * 8;
        const int c3 = t + 768,  r3 = c3 >> 2, h3 = ((c3 & 3) ^ ((r3 >> 1) & 3)) * 8;
        gA0 = A + (long)(m0 + r0) * lda + h0;
        gA1 = A + (long)(m0 + r1) * lda + h1;
        gA2 = A + (long)(m0 + r2) * lda + h2;
        gA3 = A + (long)(m0 + r3) * lda + h3;
        gB0 = B + (long)(n0 + r0) * ldb + h0;
        gB1 = B + (long)(n0 + r1) * ldb + h1;
    }

    // fragment lane bases: addr = base + slot*SZ + frag*1024 (all immediates).
    // (r>>1)&3 == (fr>>1)&3 for every fragment row, so swz is lane-constant.
    const int swz = kq8 ^ ((fr >> 1) & 3);
    const bf16* pA = As + (wr + fr) * 32 + swz * 8;
    const bf16* pB = Bs + (wc + fr) * 32 + swz * 8;

    f32x4 acc[8][4] = {};
    bf16x8 af[8], bq[4];
    int kofs = 64;   // next K-offset (elements) to stage; tiles 0,1 use 0,32

#define STAGE6(SS, ko)                                                      \
    gload_lds16(gA0 + (ko), &As[(SS) * 8192 + t * 8]);                      \
    gload_lds16(gA1 + (ko), &As[(SS) * 8192 + (t + 256) * 8]);              \
    gload_lds16(gA2 + (ko), &As[(SS) * 8192 + (t + 512) * 8]);              \
    gload_lds16(gA3 + (ko), &As[(SS) * 8192 + (t + 768) * 8]);              \
    gload_lds16(gB0 + (ko), &Bs[(SS) * 4096 + t * 8]);                      \
    gload_lds16(gB1 + (ko), &Bs[(SS) * 4096 + (t + 256) * 8]);

    // TB(CS, STG): one K-tile from slot CS.
    //   STG=1: stage tile t+2 into slot (CS+2)%3, end with vmcnt(6)+barrier
    //   STG=0: no stage, end with vmcnt(0)+barrier
    //   STG=2: last tile: no stage, no wait, no barrier
#define TB(CS, STG) do {                                                    \
    if constexpr ((STG) == 1) {                                             \
        constexpr int SS = ((CS) + 2) % 3;                                  \
        STAGE6(SS, kofs);                                                   \
        kofs += 32;                                                         \
    }                                                                       \
    DSR(af[0], pA, (CS) * 16384 + 0);                                       \
    DSR(af[1], pA, (CS) * 16384 + 1024);                                    \
    DSR(af[2], pA, (CS) * 16384 + 2048);                                    \
    DSR(af[3], pA, (CS) * 16384 + 3072);                                    \
    DSR(bq[0], pB, (CS) * 8192 + 0);                                        \
    DSR(bq[1], pB, (CS) * 8192 + 1024);                                     \
    DSR(bq[2], pB, (CS) * 8192 + 2048);                                     \
    DSR(bq[3], pB, (CS) * 8192 + 3072);                                     \
    DSR(af[4], pA, (CS) * 16384 + 4096);                                    \
    DSR(af[5], pA, (CS) * 16384 + 5120);                                    \
    DSR(af[6], pA, (CS) * 16384 + 6144);                                    \
    DSR(af[7], pA, (CS) * 16384 + 7168);                                    \
    asm volatile("s_waitcnt lgkmcnt(6)" ::: "memory");                      \
    __builtin_amdgcn_sched_barrier(0);                                      \
    __builtin_amdgcn_s_setprio(1);                                          \
    MF(0,0) MF(0,1) MF(1,0) MF(1,1) MF(2,0) MF(2,1) MF(3,0) MF(3,1)         \
    asm volatile("s_waitcnt lgkmcnt(4)" ::: "memory");                      \
    __builtin_amdgcn_sched_barrier(0);                                      \
    MF(0,2) MF(0,3) MF(1,2) MF(1,3) MF(2,2) MF(2,3) MF(3,2) MF(3,3)         \
    asm volatile("s_waitcnt lgkmcnt(0)" ::: "memory");                      \
    __builtin_amdgcn_sched_barrier(0);                                      \
    MF(4,0) MF(4,1) MF(5,0) MF(5,1) MF(6,0) MF(6,1) MF(7,0) MF(7,1)         \
    MF(4,2) MF(4,3) MF(5,2) MF(5,3) MF(6,2) MF(6,3) MF(7,2) MF(7,3)         \
    __builtin_amdgcn_s_setprio(0);                                          \
    if constexpr ((STG) == 1)                                               \
        asm volatile("s_waitcnt vmcnt(6)" ::: "memory");                    \
    else if constexpr ((STG) == 0)                                          \
        asm volatile("s_waitcnt vmcnt(0)" ::: "memory");                    \
    if constexpr ((STG) != 2) __builtin_amdgcn_s_barrier();                 \
} while (0)

    // prologue: stage tiles 0 (slot 0) and 1 (slot 1); tile-0 landed
    STAGE6(0, 0);
    STAGE6(1, 32);
    asm volatile("s_waitcnt vmcnt(6)" ::: "memory");
    __builtin_amdgcn_s_barrier();

    static_assert(NT % 3 != 0, "peel pattern assumes NT%3 in {1,2}");
    if constexpr (NT % 3 == 2) {
        TB(0, 1); TB(1, 1);
        for (int g = 0; g < (NT - 5) / 3; ++g) { TB(2, 1); TB(0, 1); TB(1, 1); }
        TB(2, 1); TB(0, 0); TB(1, 2);
    } else {
        TB(0, 1);
        for (int g = 0; g < (NT - 4) / 3; ++g) { TB(1, 1); TB(2, 1); TB(0, 1); }
        TB(1, 1); TB(2, 0); TB(0, 2);
    }
#undef TB
#undef STAGE6

    // C/D layout: col=lane&15, row=(lane>>4)*4+reg  [m89-verified]
    const int r4 = (lane >> 4) * 4;
    if constexpr (MODE == MODE_PV) {
        float* C = (float*)Cv + (long)blockIdx.z * sC;
#pragma unroll
        for (int j = 0; j < 4; j++) {
            const int col = n0 + wc + j * 16 + fr;
#pragma unroll
            for (int i = 0; i < 8; i++)
#pragma unroll
                for (int r = 0; r < 4; r++) {
                    const long row = m0 + wr + i * 16 + r4 + r;
                    C[row * ldc + col] = acc[i][j][r];
                }
        }
    } else {
        bf16* C = (bf16*)Cv + (long)blockIdx.z * sC;
#pragma unroll
        for (int j = 0; j < 4; j++) {
            const int col = n0 + wc + j * 16 + fr;
            const float bv = (MODE == MODE_QKV) ? bias[col] : 0.f;
#pragma unroll
            for (int i = 0; i < 8; i++)
#pragma unroll
                for (int r = 0; r < 4; r++) {
                    const long row = m0 + wr + i * 16 + r4 + r;
                    float v = acc[i][j][r];
                    if constexpr (MODE == MODE_QKV)
                        C[row * ldc + col] = (bf16)(v + bv);
                    else
                        C[row * ldc + col] = (bf16)__expf(alpha * v);
                }
        }
    }
}

__global__ __launch_bounds__(256) void f32_to_bf16(
    const float* __restrict__ in, bf16* __restrict__ out, long n)
{
    long i = ((long)blockIdx.x * 256 + threadIdx.x) * 4;
    if (i < n) {
        float4 v = *(const float4*)(in + i);
        bf16x4 o = { (bf16)v.x, (bf16)v.y, (bf16)v.z, (bf16)v.w };
        *(bf16x4*)(out + i) = o;
    }
}

// Vt[b][e][s] = V[b][s][e]; V has ld 3072 (inside qkv), Vt ld 2048.
__global__ __launch_bounds__(256) void transpose_v(
    const bf16* __restrict__ V, bf16* __restrict__ Vt)
{
    __shared__ bf16 tile[32][33];
    const bf16* Vb  = V  + (long)blockIdx.z * 2048 * 3072;
    bf16*       Vtb = Vt + (long)blockIdx.z * 1024 * 2048;
    const int s0 = blockIdx.x * 32, e0 = blockIdx.y * 32;
    const int tx = threadIdx.x & 31, ty = threadIdx.x >> 5;
#pragma unroll
    for (int i = 0; i < 32; i += 8)
        tile[ty + i][tx] = Vb[(long)(s0 + ty + i) * 3072 + e0 + tx];
    __syncthreads();
#pragma unroll
    for (int i = 0; i < 32; i += 8)
        Vtb[(long)(e0 + ty + i) * 2048 + s0 + tx] = tile[tx][ty + i];
}

// Per row: sum exp-scores, write fp32 out1 = Pu/l, renormalize Pu IN PLACE (bf16).
__global__ __launch_bounds__(256) void norm_rows(
    bf16* __restrict__ Pu, float* __restrict__ out1)
{
    bf16* p  = Pu   + (long)blockIdx.x * 2048;
    float* o = out1 + (long)blockIdx.x * 2048;
    const int t = threadIdx.x;
    bf16x8 v = *(const bf16x8*)(p + t * 8);
    float f[8];
    float s = 0.f;
#pragma unroll
    for (int k = 0; k < 8; k++) { f[k] = (float)v[k]; s += f[k]; }
#pragma unroll
    for (int off = 32; off > 0; off >>= 1) s += __shfl_xor(s, off);
    __shared__ float red[4];
    const int wid = t >> 6, lane = t & 63;
    if (lane == 0) red[wid] = s;
    __syncthreads();
    s = red[0] + red[1] + red[2] + red[3];
    const float inv = 1.0f / s;
    float4 a, b;
    a.x = f[0] * inv; a.y = f[1] * inv; a.z = f[2] * inv; a.w = f[3] * inv;
    b.x = f[4] * inv; b.y = f[5] * inv; b.z = f[6] * inv; b.w = f[7] * inv;
    *(float4*)(o + t * 8)     = a;
    *(float4*)(o + t * 8 + 4) = b;
    bf16x8 w;
#pragma unroll
    for (int k = 0; k < 8; k++) w[k] = (bf16)(f[k] * inv);
    *(bf16x8*)(p + t * 8) = w;
}

extern "C" void kernel_launch(void* const* d_in, const int* in_sizes, int n_in,
                              void* d_out, int out_size, void* d_ws, size_t ws_size,
                              hipStream_t stream)
{
    const int B = 4, S = 2048, E = 1024;
    const float* X    = (const float*)d_in[0];   // [B,S,E]
    const float* W    = (const float*)d_in[1];   // [3E,E]
    const float* bias = (const float*)d_in[2];   // [3E]

    float* out0 = (float*)d_out;                  // [B,S,E]
    float* out1 = out0 + (long)B * S * E;         // [B,S,S]

    // ws layout (bytes):
    //   [ 0M, 48M)  qkvb bf16 [B*S, 3072]
    //   [48M, 64M)  Vt   bf16 [B][E][S]
    //   [64M, 96M)  Pu   bf16 [B][S][S]  (exp-scores; renormalized in place)
    //   Xb [64M,80M) and Wb [80M,86.3M) overlap Pu — dead before Pu is written.
    char* ws = (char*)d_ws;
    bf16* qkvb = (bf16*)(ws);
    bf16* Vt   = (bf16*)(ws + 50331648);
    bf16* Pu   = (bf16*)(ws + 67108864);
    bf16* Xb   = (bf16*)(ws + 67108864);
    bf16* Wb   = (bf16*)(ws + 83886080);

    f32_to_bf16<<<(long)B * S * E / 1024, 256, 0, stream>>>(X, Xb, (long)B * S * E);
    f32_to_bf16<<<(long)3 * E * E / 1024, 256, 0, stream>>>(W, Wb, (long)3 * E * E);

    // qkvb = bf16(X @ W^T + b)   [M=8192, N=3072, K=1024] -> 24x32 = 768 blocks
    mfma_nt<MODE_QKV, 32><<<dim3(3 * E / 128, B * S / 256, 1), 256, 0, stream>>>(
        Xb, Wb, bias, qkvb, E, E, 3 * E, 0, 0, 0, 1.0f);

    // Vt = V^T per batch
    transpose_v<<<dim3(S / 32, E / 32, B), 256, 0, stream>>>(qkvb + 2 * E, Vt);

    // Pu = bf16(exp(Q @ K^T / 32))  [2048x2048, K=1024] x4 -> 512 blocks
    mfma_nt<MODE_SCORES, 32><<<dim3(S / 128, S / 256, B), 256, 0, stream>>>(
        qkvb, qkvb + E, nullptr, Pu, 3 * E, 3 * E, S,
        (long)S * 3 * E, (long)S * 3 * E, (long)S * S, 0.03125f);

    // out1 = Pu / rowsum  (fp32); Pu <- normalized bf16 in place
    norm_rows<<<B * S, 256, 0, stream>>>(Pu, out1);

    // out0 = P @ V  (= Pu @ Vt^T, NT)  [2048x1024, K=2048] x4 -> 256 blocks
    mfma_nt<MODE_PV, 64><<<dim3(E / 128, S / 256, B), 256, 0, stream>>>(
        Pu, Vt, nullptr, out0, S, S, E,
        (long)S * S, (long)E * S, (long)S * E, 1.0f);
}